// Round 5
// baseline (271.184 us; speedup 1.0000x reference)
//
#include <hip/hip_runtime.h>

#define C_CLASSES 2048
#define F_EMBED   128
#define N_ROWS    16384

constexpr float TAU    = 32.0f;
constexpr float LOG2E  = 1.4426950408889634f;
constexpr float LN2    = 0.6931471805599453f;
constexpr float TAU2   = TAU * LOG2E;     // 46.166241...
constexpr float ZS2    = 64.0f * LOG2E;   // 92.332483...  (fixed logit shift, z+64 in [-64,64])
constexpr float AL2    = -0.9f * LOG2E;   // -1.298425...

typedef __bf16 bf16x8 __attribute__((ext_vector_type(8)));
typedef float  f32x4  __attribute__((ext_vector_type(4)));

__device__ __forceinline__ float wsum64(float v) {
#pragma unroll
  for (int m = 1; m < 64; m <<= 1) v += __shfl_xor(v, m, 64);
  return v;
}

// ---------------- prep: per-class data ----------------
// mu = l2norm(means[c]); ic = exp(-clip(lv,0,6)); w2 = -2*mu*ic; s3 = sum mu^2*ic
__global__ __launch_bounds__(256) void prep_classes_k(
    const float* __restrict__ means, const float* __restrict__ log_vars,
    __bf16* __restrict__ icb, __bf16* __restrict__ w2b,
    float* __restrict__ s3, float* __restrict__ out0) {
  const int c    = blockIdx.x * 4 + (threadIdx.x >> 6);
  const int lane = threadIdx.x & 63;
  const size_t base = (size_t)c * F_EMBED;
  const float m0 = means[base + lane], m1 = means[base + lane + 64];
  const float ss = wsum64(m0 * m0 + m1 * m1);
  const float inv = 1.0f / fmaxf(sqrtf(ss), 1e-12f);
  const float mu0 = m0 * inv, mu1 = m1 * inv;
  const float lv0 = fminf(fmaxf(log_vars[base + lane], 0.0f), 6.0f);
  const float lv1 = fminf(fmaxf(log_vars[base + lane + 64], 0.0f), 6.0f);
  const float ic0 = __expf(-lv0), ic1 = __expf(-lv1);
  const float s3p = wsum64(mu0 * mu0 * ic0 + mu1 * mu1 * ic1);
  icb[base + lane]      = (__bf16)ic0;
  icb[base + lane + 64] = (__bf16)ic1;
  w2b[base + lane]      = (__bf16)(-2.0f * mu0 * ic0);
  w2b[base + lane + 64] = (__bf16)(-2.0f * mu1 * ic1);
  if (lane == 0) s3[c] = s3p;
  if (c == 0 && lane == 0) out0[0] = 0.0f;  // loss accumulator (d_out re-poisoned each call)
}

// ---------------- prep: per-row data ----------------
__global__ __launch_bounds__(256) void prep_rows_k(
    const float* __restrict__ X, __bf16* __restrict__ xnb, __bf16* __restrict__ xn2b) {
  const int n    = blockIdx.x * 4 + (threadIdx.x >> 6);
  const int lane = threadIdx.x & 63;
  const size_t base = (size_t)n * F_EMBED;
  const float x0 = X[base + lane], x1 = X[base + lane + 64];
  const float ss = wsum64(x0 * x0 + x1 * x1);
  const float inv = 1.0f / fmaxf(sqrtf(ss), 1e-12f);
  const float a0 = x0 * inv, a1 = x1 * inv;
  xnb[base + lane]       = (__bf16)a0;
  xnb[base + lane + 64]  = (__bf16)a1;
  xn2b[base + lane]      = (__bf16)(a0 * a0);
  xn2b[base + lane + 64] = (__bf16)(a1 * a1);
}

// ---------------- fused main (swapped operands: D^T tiles) ----------------
// Grid: 512 blocks x 512 thr (2 blocks/CU). Block owns 32 rows. Wave w:
// rowg = w&1 (16 rows), q = w>>1 (512 classes as 8 interleaved 64-col chunks,
// ci = q+4g, so the 4 q-waves write ADJACENT 256B chunks per row -> L2 merge).
// MFMA: A = class frags, B = row frags  =>  lane holds 4 consecutive classes
// of ONE row per acc: row-contiguous stores, scalar lsum/dTv, no LDS transpose.
__global__ __launch_bounds__(512, 4) void mahal_main_k(
    const __bf16* __restrict__ xnb, const __bf16* __restrict__ xn2b,
    const __bf16* __restrict__ icb, const __bf16* __restrict__ w2b,
    const float* __restrict__ s3, const int* __restrict__ T,
    float* __restrict__ out) {
  __shared__ int   Tl[32];
  __shared__ float Ls[8][16];
  __shared__ float Dt[8][16];
  const int tid  = threadIdx.x;
  const int w    = tid >> 6;
  const int lane = tid & 63;
  const int lo   = lane & 15;
  const int hi   = lane >> 4;
  const int rowg = w & 1;
  const int q    = w >> 1;
  const int rowbase = blockIdx.x * 32;
  if (tid < 32) Tl[tid] = T[rowbase + tid];
  __syncthreads();

  const int myrow = rowg * 16 + lo;     // 0..31 within block
  const int tTl   = Tl[myrow];          // target class of this lane's row

  // row ("B") fragments: lane holds X[rowbase+myrow][k = kg*32 + hi*8 + j]
  bf16x8 axn[4], ax2[4];
  {
    const size_t rb = (size_t)(rowbase + myrow) * F_EMBED + hi * 8;
#pragma unroll
    for (int kg = 0; kg < 4; ++kg) {
      axn[kg] = *(const bf16x8*)(xnb  + rb + kg * 32);
      ax2[kg] = *(const bf16x8*)(xn2b + rb + kg * 32);
    }
  }

  float lsum = 0.0f, dTv = 0.0f;
  float* __restrict__ outH = out + 1 + (size_t)(rowbase + myrow) * C_CLASSES;

  // class ("A") fragments: single-buffered, reloaded for t+1 right after the
  // MFMAs of t (and BEFORE the epilogue stores of t -> load-waits never have
  // to drain stores through the FIFO vmcnt).
  bf16x8 cic[4], cw2[4];
  {
    const size_t cb = (size_t)(q * 64 + lo) * F_EMBED + hi * 8;  // t=0: ci=q, ctl=0
#pragma unroll
    for (int kg = 0; kg < 4; ++kg) {
      cic[kg] = *(const bf16x8*)(icb + cb + kg * 32);
      cw2[kg] = *(const bf16x8*)(w2b + cb + kg * 32);
    }
  }

  for (int t = 0; t < 32; ++t) {
    const int ctbase = (q + 4 * (t >> 2)) * 64 + (t & 3) * 16;

    f32x4 acc = {0.f, 0.f, 0.f, 0.f};
#pragma unroll
    for (int kg = 0; kg < 4; ++kg) {
      acc = __builtin_amdgcn_mfma_f32_16x16x32_bf16(cic[kg], ax2[kg], acc, 0, 0, 0);
      acc = __builtin_amdgcn_mfma_f32_16x16x32_bf16(cw2[kg], axn[kg], acc, 0, 0, 0);
    }

    if (t < 31) {   // prefetch next class tile (issued before any store of t)
      const int t2 = t + 1;
      const int nb = (q + 4 * (t2 >> 2)) * 64 + (t2 & 3) * 16;
      const size_t cb = (size_t)(nb + lo) * F_EMBED + hi * 8;
#pragma unroll
      for (int kg = 0; kg < 4; ++kg) {
        cic[kg] = *(const bf16x8*)(icb + cb + kg * 32);
        cw2[kg] = *(const bf16x8*)(w2b + cb + kg * 32);
      }
    }

    // epilogue: lane owns row (rowbase+myrow), classes ctbase + hi*4 + r
    const f32x4 s3v = *(const f32x4*)(s3 + ctbase + hi * 4);
#pragma unroll
    for (int r = 0; r < 4; ++r) {
      const int   c   = ctbase + hi * 4 + r;
      const float D   = acc[r] + s3v[r];
      const bool  isT = (c == tTl);
      outH[c] = isT ? 1.0f : exp2f(AL2 * D);
      lsum += exp2f(ZS2 - TAU2 * D);
      if (isT) dTv = D;
    }
  }

  // reduce over the 4 hi-lanes that share each row
  lsum += __shfl_xor(lsum, 16, 64);
  lsum += __shfl_xor(lsum, 32, 64);
  dTv  += __shfl_xor(dTv, 16, 64);
  dTv  += __shfl_xor(dTv, 32, 64);
  if (hi == 0) { Ls[w][lo] = lsum; Dt[w][lo] = dTv; }
  __syncthreads();

  if (w == 0) {
    float loss = 0.0f;
    if (lane < 32) {
      const int rr = lane & 15, rgg = lane >> 4;
      float L = 0.f, Dv = 0.f;
#pragma unroll
      for (int qq = 0; qq < 4; ++qq) {
        L  += Ls[2 * qq + rgg][rr];
        Dv += Dt[2 * qq + rgg][rr];
      }
      loss = TAU * Dv + __log2f(L) * LN2 - 64.0f;  // -logp[n, T[n]]
    }
    loss = wsum64(loss);
    if (lane == 0) atomicAdd(out, loss * (1.0f / N_ROWS));
  }
}

extern "C" void kernel_launch(void* const* d_in, const int* in_sizes, int n_in,
                              void* d_out, int out_size, void* d_ws, size_t ws_size,
                              hipStream_t stream) {
  const float* X        = (const float*)d_in[0];
  const int*   T        = (const int*)d_in[1];
  const float* means    = (const float*)d_in[2];
  const float* log_vars = (const float*)d_in[3];
  float* out = (float*)d_out;

  // workspace layout (~9.02 MB, 16B-aligned chunks)
  char* ws = (char*)d_ws;
  __bf16* icb  = (__bf16*)ws;                                            // 512 KB
  __bf16* w2b  = (__bf16*)(ws + (512u << 10));                           // 512 KB
  float*  s3   = (float*)(ws + (1u << 20));                              // 8 KB
  __bf16* xnb  = (__bf16*)(ws + (1u << 20) + (16u << 10));               // 4 MB
  __bf16* xn2b = (__bf16*)(ws + (1u << 20) + (16u << 10) + (4u << 20));  // 4 MB

  prep_classes_k<<<C_CLASSES / 4, 256, 0, stream>>>(means, log_vars, icb, w2b, s3, out);
  prep_rows_k<<<N_ROWS / 4, 256, 0, stream>>>(X, xnb, xn2b);
  mahal_main_k<<<N_ROWS / 32, 512, 0, stream>>>(xnb, xn2b, icb, w2b, s3, T, out);
}

// Round 6
// 266.703 us; speedup vs baseline: 1.0168x; 1.0168x over previous
//
#include <hip/hip_runtime.h>

#define C_CLASSES 2048
#define F_EMBED   128
#define N_ROWS    16384

constexpr float TAU    = 32.0f;
constexpr float LOG2E  = 1.4426950408889634f;
constexpr float LN2    = 0.6931471805599453f;
constexpr float TAU2   = TAU * LOG2E;     // 46.166241...
constexpr float ZS2    = 64.0f * LOG2E;   // 92.332483...  (fixed logit shift, z+64 in [-64,64])
constexpr float AL2    = -0.9f * LOG2E;   // -1.298425...

typedef __bf16 bf16x8 __attribute__((ext_vector_type(8)));
typedef float  f32x4  __attribute__((ext_vector_type(4)));

__device__ __forceinline__ float wsum64(float v) {
#pragma unroll
  for (int m = 1; m < 64; m <<= 1) v += __shfl_xor(v, m, 64);
  return v;
}

// ---------------- prep: per-class data ----------------
// mu = l2norm(means[c]); ic = exp(-clip(lv,0,6)); w2 = -2*mu*ic; s3 = sum mu^2*ic
__global__ __launch_bounds__(256) void prep_classes_k(
    const float* __restrict__ means, const float* __restrict__ log_vars,
    __bf16* __restrict__ icb, __bf16* __restrict__ w2b,
    float* __restrict__ s3, float* __restrict__ out0) {
  const int c    = blockIdx.x * 4 + (threadIdx.x >> 6);
  const int lane = threadIdx.x & 63;
  const size_t base = (size_t)c * F_EMBED;
  const float m0 = means[base + lane], m1 = means[base + lane + 64];
  const float ss = wsum64(m0 * m0 + m1 * m1);
  const float inv = 1.0f / fmaxf(sqrtf(ss), 1e-12f);
  const float mu0 = m0 * inv, mu1 = m1 * inv;
  const float lv0 = fminf(fmaxf(log_vars[base + lane], 0.0f), 6.0f);
  const float lv1 = fminf(fmaxf(log_vars[base + lane + 64], 0.0f), 6.0f);
  const float ic0 = __expf(-lv0), ic1 = __expf(-lv1);
  const float s3p = wsum64(mu0 * mu0 * ic0 + mu1 * mu1 * ic1);
  icb[base + lane]      = (__bf16)ic0;
  icb[base + lane + 64] = (__bf16)ic1;
  w2b[base + lane]      = (__bf16)(-2.0f * mu0 * ic0);
  w2b[base + lane + 64] = (__bf16)(-2.0f * mu1 * ic1);
  if (lane == 0) s3[c] = s3p;
  if (c == 0 && lane == 0) out0[0] = 0.0f;  // loss accumulator (d_out re-poisoned each call)
}

// ---------------- prep: per-row data ----------------
__global__ __launch_bounds__(256) void prep_rows_k(
    const float* __restrict__ X, __bf16* __restrict__ xnb, __bf16* __restrict__ xn2b) {
  const int n    = blockIdx.x * 4 + (threadIdx.x >> 6);
  const int lane = threadIdx.x & 63;
  const size_t base = (size_t)n * F_EMBED;
  const float x0 = X[base + lane], x1 = X[base + lane + 64];
  const float ss = wsum64(x0 * x0 + x1 * x1);
  const float inv = 1.0f / fmaxf(sqrtf(ss), 1e-12f);
  const float a0 = x0 * inv, a1 = x1 * inv;
  xnb[base + lane]       = (__bf16)a0;
  xnb[base + lane + 64]  = (__bf16)a1;
  xn2b[base + lane]      = (__bf16)(a0 * a0);
  xn2b[base + lane + 64] = (__bf16)(a1 * a1);
}

// ---------------- fused main (chunked store-burst version) ----------------
// Grid: 512 blocks x 512 thr (2 blocks/CU). Block owns 32 rows. Wave w:
// rowg = w&1 (16 rows), q = w>>1 owns the CONTIGUOUS 512-class span
// [q*512, (q+1)*512) as 8 chunks of 64 classes. Per chunk: 4 MFMA tiles
// accumulate into accs[4], then ONE store burst writes 256B contiguous per
// row (4 x dwordx4 per lane, back-to-back) -> 128B lines fully dirty within
// a few instructions -> L2 merges -> no half-line writeback amplification.
__global__ __launch_bounds__(512, 4) void mahal_main_k(
    const __bf16* __restrict__ xnb, const __bf16* __restrict__ xn2b,
    const __bf16* __restrict__ icb, const __bf16* __restrict__ w2b,
    const float* __restrict__ s3, const int* __restrict__ T,
    float* __restrict__ out) {
  __shared__ int   Tl[32];
  __shared__ float Ls[8][16];
  __shared__ float Dt[8][16];
  const int tid  = threadIdx.x;
  const int w    = tid >> 6;
  const int lane = tid & 63;
  const int lo   = lane & 15;
  const int hi   = lane >> 4;
  const int rowg = w & 1;
  const int q    = w >> 1;
  const int rowbase = blockIdx.x * 32;
  if (tid < 32) Tl[tid] = T[rowbase + tid];
  __syncthreads();

  const int myrow = rowg * 16 + lo;     // 0..31 within block
  const int tTl   = Tl[myrow];          // target class of this lane's row

  // row ("B") fragments: lane holds X[rowbase+myrow][k = kg*32 + hi*8 + j]
  bf16x8 axn[4], ax2[4];
  {
    const size_t rb = (size_t)(rowbase + myrow) * F_EMBED + hi * 8;
#pragma unroll
    for (int kg = 0; kg < 4; ++kg) {
      axn[kg] = *(const bf16x8*)(xnb  + rb + kg * 32);
      ax2[kg] = *(const bf16x8*)(xn2b + rb + kg * 32);
    }
  }

  float lsum = 0.0f, dTv = 0.0f;
  float* __restrict__ outH = out + 1 + (size_t)(rowbase + myrow) * C_CLASSES;

  for (int g = 0; g < 8; ++g) {
    const int chunk = q * 8 + g;              // contiguous span per wave
    f32x4 accs[4];                            // 4 tiles = 64 classes, static idx

    // compute phase: 4 tiles x (8 loads + 8 MFMAs)
#pragma unroll
    for (int s = 0; s < 4; ++s) {
      const size_t cb = (size_t)(chunk * 64 + s * 16 + lo) * F_EMBED + hi * 8;
      bf16x8 cic[4], cw2[4];
#pragma unroll
      for (int kg = 0; kg < 4; ++kg) {
        cic[kg] = *(const bf16x8*)(icb + cb + kg * 32);
        cw2[kg] = *(const bf16x8*)(w2b + cb + kg * 32);
      }
      f32x4 acc = {0.f, 0.f, 0.f, 0.f};
#pragma unroll
      for (int kg = 0; kg < 4; ++kg) {
        acc = __builtin_amdgcn_mfma_f32_16x16x32_bf16(cic[kg], ax2[kg], acc, 0, 0, 0);
        acc = __builtin_amdgcn_mfma_f32_16x16x32_bf16(cw2[kg], axn[kg], acc, 0, 0, 0);
      }
      accs[s] = acc;
    }

    // flush phase: 4 x dwordx4 per lane, 256B contiguous per row, back-to-back
#pragma unroll
    for (int s = 0; s < 4; ++s) {
      const int cb0 = chunk * 64 + s * 16 + hi * 4;   // lane's 4 classes
      const f32x4 s3v = *(const f32x4*)(s3 + cb0);
      f32x4 hv;
#pragma unroll
      for (int r = 0; r < 4; ++r) {
        const float D   = accs[s][r] + s3v[r];
        const bool  isT = (cb0 + r == tTl);
        hv[r] = isT ? 1.0f : exp2f(AL2 * D);
        lsum += exp2f(ZS2 - TAU2 * D);
        if (isT) dTv = D;
      }
      __builtin_memcpy(outH + cb0, &hv, 16);  // unaligned-safe 16B store
    }
  }

  // reduce over the 4 hi-lanes that share each row
  lsum += __shfl_xor(lsum, 16, 64);
  lsum += __shfl_xor(lsum, 32, 64);
  dTv  += __shfl_xor(dTv, 16, 64);
  dTv  += __shfl_xor(dTv, 32, 64);
  if (hi == 0) { Ls[w][lo] = lsum; Dt[w][lo] = dTv; }
  __syncthreads();

  if (w == 0) {
    float loss = 0.0f;
    if (lane < 32) {
      const int rr = lane & 15, rgg = lane >> 4;
      float L = 0.f, Dv = 0.f;
#pragma unroll
      for (int qq = 0; qq < 4; ++qq) {
        L  += Ls[2 * qq + rgg][rr];
        Dv += Dt[2 * qq + rgg][rr];
      }
      loss = TAU * Dv + __log2f(L) * LN2 - 64.0f;  // -logp[n, T[n]]
    }
    loss = wsum64(loss);
    if (lane == 0) atomicAdd(out, loss * (1.0f / N_ROWS));
  }
}

extern "C" void kernel_launch(void* const* d_in, const int* in_sizes, int n_in,
                              void* d_out, int out_size, void* d_ws, size_t ws_size,
                              hipStream_t stream) {
  const float* X        = (const float*)d_in[0];
  const int*   T        = (const int*)d_in[1];
  const float* means    = (const float*)d_in[2];
  const float* log_vars = (const float*)d_in[3];
  float* out = (float*)d_out;

  // workspace layout (~9.02 MB, 16B-aligned chunks)
  char* ws = (char*)d_ws;
  __bf16* icb  = (__bf16*)ws;                                            // 512 KB
  __bf16* w2b  = (__bf16*)(ws + (512u << 10));                           // 512 KB
  float*  s3   = (float*)(ws + (1u << 20));                              // 8 KB
  __bf16* xnb  = (__bf16*)(ws + (1u << 20) + (16u << 10));               // 4 MB
  __bf16* xn2b = (__bf16*)(ws + (1u << 20) + (16u << 10) + (4u << 20));  // 4 MB

  prep_classes_k<<<C_CLASSES / 4, 256, 0, stream>>>(means, log_vars, icb, w2b, s3, out);
  prep_rows_k<<<N_ROWS / 4, 256, 0, stream>>>(X, xnb, xn2b);
  mahal_main_k<<<N_ROWS / 32, 512, 0, stream>>>(xnb, xn2b, icb, w2b, s3, T, out);
}